// Round 3
// baseline (934.926 us; speedup 1.0000x reference)
//
#include <hip/hip_runtime.h>
#include <stdint.h>

#define NROWS 65536
#define IDIM 2048

typedef __attribute__((ext_vector_type(4))) float v4f;
typedef __attribute__((ext_vector_type(8))) short v8s;

__device__ __forceinline__ unsigned short f2bf(float f) {
  unsigned int u = __float_as_uint(f);
  u += 0x7fffu + ((u >> 16) & 1u);          // round-to-nearest-even
  return (unsigned short)(u >> 16);
}

struct Expert {
  const unsigned short* w1t;   // [HN][2048] bf16 (row n, contiguous in k)
  const float* b1;
  const unsigned short* w2t;   // [HN/2][HN] bf16
  const float* b2;
  const float* w3;             // [HN/2]
  const float* b3;             // [1]
  const int* idx;              // this expert's row-index list
  const int* count;
};
struct Quad { Expert e[4]; };

struct ConvArgs {
  const float* W1[4]; const float* W2[4];
  unsigned short* w1t[4]; unsigned short* w2t[4];
  int HN[4];
};

// ---------------- fused prep: y==0 bucket rows, y>=1 convert expert y-1 ----------------
__global__ void prep_all(const int* __restrict__ labels, float* __restrict__ out,
                         int* __restrict__ counts, int* __restrict__ idx, ConvArgs c)
{
  const int t = threadIdx.x;
  if (blockIdx.y == 0) {
    // bucket rows by label (blocks 256.. are idle but harmless)
    __shared__ int lcnt[4];
    __shared__ int lbase[4];
    if (t < 4) lcnt[t] = 0;
    __syncthreads();
    const int i = blockIdx.x * blockDim.x + t;
    int lbl = -1, pos = 0;
    if (i < NROWS) {
      lbl = labels[i];
      if (lbl >= 0 && lbl <= 3) {
        pos = atomicAdd(&lcnt[lbl], 1);
      } else {
        out[i] = 0.f;   // rows with unknown label output 0 (d_out is poisoned)
        lbl = -1;
      }
    }
    __syncthreads();
    if (t < 4) lbase[t] = atomicAdd(&counts[t], lcnt[t]);
    __syncthreads();
    if (lbl >= 0) idx[lbl * NROWS + lbase[lbl] + pos] = i;
  } else {
    const int e = blockIdx.y - 1;
    const int HN = c.HN[e];
    const int HN2 = HN >> 1;
    const int n1 = IDIM * HN;
    const int total = n1 + HN * HN2;
    const int i = blockIdx.x * blockDim.x + t;
    if (i >= total) return;
    if (i < n1) {
      int nn = i / IDIM, k = i - nn * IDIM;
      c.w1t[e][i] = f2bf(c.W1[e][k * HN + nn]);        // w1t[n][k] = W1[k][n]
    } else {
      int j = i - n1;
      int nn = j / HN, k = j - nn * HN;
      c.w2t[e][j] = f2bf(c.W2[e][k * HN2 + nn]);       // w2t[n][k] = W2[k][n]
    }
  }
}

// ---------------- main fused kernel ----------------
// Fully barrier-free: with TM=64 and staging row = lane>>2, each wave stages and
// consumes only its own 16 A-rows (wave-private LDS double-buffer). B (w1t,
// 1.5 MB total, L2-resident) and W2T (16 KB) are loaded directly from L2 into
// fragments -> sB and all __syncthreads deleted. h1 in disjoint wave-private LDS.
// LDS: 2*64*40*2 + 64*136*2 = 27648 B -> 5 blocks/CU; ~16-20 waves/CU.
template<int HN>
__device__ __forceinline__ void moe_body(const float* __restrict__ x, float* __restrict__ out,
                                         const Expert E, char* smem)
{
  constexpr int HN2 = HN / 2;
  constexpr int TM  = 64;
  constexpr int BK  = 32;
  constexpr int AW  = BK + 8;     // 40: padded row stride (80 B), 16B-aligned rows
  constexpr int H1W = HN + 8;
  constexpr int NF1 = HN / 16;
  constexpr int NF2 = HN2 / 16;

  unsigned short* sA0 = (unsigned short*)smem;          // [TM][AW]
  unsigned short* sA1 = sA0 + TM * AW;                  // [TM][AW]
  unsigned short* sH1 = sA1 + TM * AW;                  // [TM][H1W] wave-private slices

  const int cnt = *E.count;
  const int tile0 = blockIdx.x * TM;
  if (tile0 >= cnt) return;
  const int rv = min(TM, cnt - tile0);

  const int t    = threadIdx.x;
  const int lane = t & 63;
  const int l15  = lane & 15;
  const int quad = lane >> 4;
  const int m0   = (t >> 6) * 16;    // wave's 16 rows of the 64-row tile

  // A staging: lane owns row m0 + (lane>>2), 8 cols starting at (lane&3)*8.
  // Wave w writes rows 16w..16w+15 == exactly the rows whose fragments it reads.
  const int ar = m0 + (lane >> 2);
  const int ac = (lane & 3) * 8;
  const int ridA = E.idx[tile0 + (ar < rv ? ar : 0)];
  const float* ap = x + (size_t)ridA * IDIM + ac;

  const unsigned short* bp = E.w1t + (size_t)l15 * IDIM + quad * 8;

  v4f acc[NF1];
  #pragma unroll
  for (int ni = 0; ni < NF1; ++ni) acc[ni] = (v4f){0.f, 0.f, 0.f, 0.f};

  // prologue: stage k=0 into buf0
  {
    v4f va = *(const v4f*)(ap);
    v4f vb = *(const v4f*)(ap + 4);
    v8s pk;
    pk[0]=(short)f2bf(va[0]); pk[1]=(short)f2bf(va[1]); pk[2]=(short)f2bf(va[2]); pk[3]=(short)f2bf(va[3]);
    pk[4]=(short)f2bf(vb[0]); pk[5]=(short)f2bf(vb[1]); pk[6]=(short)f2bf(vb[2]); pk[7]=(short)f2bf(vb[3]);
    *(v8s*)&sA0[ar * AW + ac] = pk;
  }

  #pragma unroll 1
  for (int k0 = 0; k0 < IDIM; k0 += 2 * BK) {
    // half 1: prefetch k0+BK -> buf1; compute buf0 @ k0 (B direct from L2)
    {
      v4f va = *(const v4f*)(ap + k0 + BK);
      v4f vb = *(const v4f*)(ap + k0 + BK + 4);
      v8s b[NF1];
      #pragma unroll
      for (int ni = 0; ni < NF1; ++ni)
        b[ni] = *(const v8s*)(bp + (size_t)(ni * 16) * IDIM + k0);
      v8s a = *(const v8s*)&sA0[(m0 + l15) * AW + quad * 8];
      #pragma unroll
      for (int ni = 0; ni < NF1; ++ni)
        acc[ni] = __builtin_amdgcn_mfma_f32_16x16x32_bf16(a, b[ni], acc[ni], 0, 0, 0);
      v8s pk;
      pk[0]=(short)f2bf(va[0]); pk[1]=(short)f2bf(va[1]); pk[2]=(short)f2bf(va[2]); pk[3]=(short)f2bf(va[3]);
      pk[4]=(short)f2bf(vb[0]); pk[5]=(short)f2bf(vb[1]); pk[6]=(short)f2bf(vb[2]); pk[7]=(short)f2bf(vb[3]);
      *(v8s*)&sA1[ar * AW + ac] = pk;
    }
    // half 2: prefetch k0+2*BK -> buf0 (if any); compute buf1 @ k0+BK
    {
      const int kn = k0 + 2 * BK;
      const bool more = (kn < IDIM);
      v4f va, vb;
      if (more) {
        va = *(const v4f*)(ap + kn);
        vb = *(const v4f*)(ap + kn + 4);
      }
      v8s b[NF1];
      #pragma unroll
      for (int ni = 0; ni < NF1; ++ni)
        b[ni] = *(const v8s*)(bp + (size_t)(ni * 16) * IDIM + k0 + BK);
      v8s a = *(const v8s*)&sA1[(m0 + l15) * AW + quad * 8];
      #pragma unroll
      for (int ni = 0; ni < NF1; ++ni)
        acc[ni] = __builtin_amdgcn_mfma_f32_16x16x32_bf16(a, b[ni], acc[ni], 0, 0, 0);
      if (more) {
        v8s pk;
        pk[0]=(short)f2bf(va[0]); pk[1]=(short)f2bf(va[1]); pk[2]=(short)f2bf(va[2]); pk[3]=(short)f2bf(va[3]);
        pk[4]=(short)f2bf(vb[0]); pk[5]=(short)f2bf(vb[1]); pk[6]=(short)f2bf(vb[2]); pk[7]=(short)f2bf(vb[3]);
        *(v8s*)&sA0[ar * AW + ac] = pk;
      }
    }
  }

  // epilogue 1: h1 = relu(acc + b1) -> wave-private LDS slice (no barrier needed)
  unsigned short* myH1 = sH1 + m0 * H1W;
  #pragma unroll
  for (int ni = 0; ni < NF1; ++ni) {
    const int col = ni * 16 + l15;
    const float b1v = E.b1[col];
    #pragma unroll
    for (int r = 0; r < 4; ++r)
      myH1[(quad * 4 + r) * H1W + col] = f2bf(fmaxf(acc[ni][r] + b1v, 0.f));
  }

  // layer 2: h2 = relu(h1 @ W2 + b2), K = HN; W2T fragments direct from L2
  v4f acc2[NF2];
  #pragma unroll
  for (int ni = 0; ni < NF2; ++ni) acc2[ni] = (v4f){0.f, 0.f, 0.f, 0.f};
  #pragma unroll
  for (int ks = 0; ks < HN / 32; ++ks) {
    v8s a2 = *(const v8s*)&myH1[l15 * H1W + ks * 32 + quad * 8];
    #pragma unroll
    for (int ni = 0; ni < NF2; ++ni) {
      v8s b2 = *(const v8s*)(E.w2t + (size_t)(ni * 16 + l15) * HN + ks * 32 + quad * 8);
      acc2[ni] = __builtin_amdgcn_mfma_f32_16x16x32_bf16(a2, b2, acc2[ni], 0, 0, 0);
    }
  }

  // layer 3: out = relu(h2) @ W3 + b3, in-register shuffle reduce over 16 lanes
  float w3v[NF2], b2v[NF2];
  #pragma unroll
  for (int ni = 0; ni < NF2; ++ni) {
    const int c = ni * 16 + l15;
    w3v[ni] = E.w3[c];
    b2v[ni] = E.b2[c];
  }
  const float b3v = E.b3[0];
  #pragma unroll
  for (int r = 0; r < 4; ++r) {
    float s = 0.f;
    #pragma unroll
    for (int ni = 0; ni < NF2; ++ni)
      s = fmaf(fmaxf(acc2[ni][r] + b2v[ni], 0.f), w3v[ni], s);
    s += __shfl_xor(s, 1);
    s += __shfl_xor(s, 2);
    s += __shfl_xor(s, 4);
    s += __shfl_xor(s, 8);
    if (l15 == 0) {
      const int row = m0 + quad * 4 + r;
      if (row < rv) out[E.idx[tile0 + row]] = s + b3v;
    }
  }
}

__global__ __launch_bounds__(256, 4)
void moe_main(const float* __restrict__ x, float* __restrict__ out, Quad q)
{
  // LDS (HN=128 worst case): 2*64*40*2 + 64*136*2 = 27648 B -> 5 blocks/CU
  __shared__ __align__(16) char smem[27648];
  const int e = blockIdx.y;
  if (e < 2) moe_body<64>(x, out, q.e[e], smem);
  else       moe_body<128>(x, out, q.e[e], smem);
}

// ---------------- host ----------------
extern "C" void kernel_launch(void* const* d_in, const int* in_sizes, int n_in,
                              void* d_out, int out_size, void* d_ws, size_t ws_size,
                              hipStream_t stream)
{
  const float* x   = (const float*)d_in[0];
  const int* labels = (const int*)d_in[1];
  float* out = (float*)d_out;

  char* ws = (char*)d_ws;
  int* counts = (int*)ws;                       // 16 B
  int* idx = (int*)(ws + 256);                  // 4 * 65536 ints = 1 MiB
  static const int HNs[4] = {64, 64, 128, 128};
  unsigned short* w1t[4];
  unsigned short* w2t[4];
  size_t off = 256 + (size_t)4 * NROWS * 4;
  for (int e = 0; e < 4; ++e) { w1t[e] = (unsigned short*)(ws + off); off += (size_t)IDIM * HNs[e] * 2; }
  for (int e = 0; e < 4; ++e) { w2t[e] = (unsigned short*)(ws + off); off += (size_t)HNs[e] * (HNs[e] / 2) * 2; }

  hipMemsetAsync(counts, 0, 4 * sizeof(int), stream);

  ConvArgs ca;
  for (int e = 0; e < 4; ++e) {
    ca.W1[e] = (const float*)d_in[2 + 6 * e + 0];
    ca.W2[e] = (const float*)d_in[2 + 6 * e + 2];
    ca.w1t[e] = w1t[e];
    ca.w2t[e] = w2t[e];
    ca.HN[e] = HNs[e];
  }
  // y=0: build lists (first 256 x-blocks active); y=1..4: convert expert weights
  // max conv total = IDIM*128 + 128*64 = 270336 -> 1056 blocks of 256
  prep_all<<<dim3(1056, 5), dim3(256), 0, stream>>>(labels, out, counts, idx, ca);

  Quad q;
  for (int e = 0; e < 4; ++e) {
    q.e[e].w1t = w1t[e];
    q.e[e].b1  = (const float*)d_in[2 + 6 * e + 1];
    q.e[e].w2t = w2t[e];
    q.e[e].b2  = (const float*)d_in[2 + 6 * e + 3];
    q.e[e].w3  = (const float*)d_in[2 + 6 * e + 4];
    q.e[e].b3  = (const float*)d_in[2 + 6 * e + 5];
    q.e[e].idx = idx + (size_t)e * NROWS;
    q.e[e].count = counts + e;
  }
  moe_main<<<dim3(NROWS / 64, 4), dim3(256), 0, stream>>>(x, out, q);
}